// Round 1
// 102.000 us; speedup vs baseline: 1.0408x; 1.0408x over previous
//
#include <hip/hip_runtime.h>

// loss = 0.5 * ( sum_j[(y-mu)^2/sigma + log(sigma)] + NT*log(2pi) ) / (NT*BS)
// over the LAST row only (the torch loop overwrites `loss` each iteration,
// so only sample bs-1 survives).
//
// nt = 2048 floats = 512 float4 per array. One block, 512 threads (8 waves):
// each thread issues exactly one float4 load from each of mu/sigma/y — all
// loads independent, single HBM round-trip (row is L3-cold because the
// harness's 268 MB re-poison fills sweep the 256 MB L3 every iteration).

#define LOG_2PI 1.8378770664093453f

__global__ __launch_bounds__(512) void criterion_lastrow_kernel(
    const float4* __restrict__ mu4,
    const float4* __restrict__ sig4,
    const float4* __restrict__ y4,
    float* __restrict__ out,
    int nt, int bs)
{
    const int tid = threadIdx.x;   // 0..511, exactly nt/4 threads

    // Three independent 16B loads — compiler emits global_load_dwordx4 x3
    // back-to-back; latency overlapped across 8 waves.
    float4 m = mu4[tid];
    float4 s = sig4[tid];
    float4 t = y4[tid];

    float d0 = t.x - m.x;
    float d1 = t.y - m.y;
    float d2 = t.z - m.z;
    float d3 = t.w - m.w;

    float acc = d0 * d0 / s.x + logf(s.x);
    acc      += d1 * d1 / s.y + logf(s.y);
    acc      += d2 * d2 / s.z + logf(s.z);
    acc      += d3 * d3 / s.w + logf(s.w);

    // wave (64-lane) butterfly reduction
    #pragma unroll
    for (int off = 32; off > 0; off >>= 1)
        acc += __shfl_down(acc, off, 64);

    __shared__ float wsum[8];
    const int wave = tid >> 6;
    const int lane = tid & 63;
    if (lane == 0) wsum[wave] = acc;
    __syncthreads();

    if (tid == 0) {
        float total = 0.0f;
        #pragma unroll
        for (int w = 0; w < 8; ++w) total += wsum[w];
        float logprob_neg = 0.5f * (total + (float)nt * LOG_2PI);
        out[0] = logprob_neg / ((float)nt * (float)bs);
    }
}

extern "C" void kernel_launch(void* const* d_in, const int* in_sizes, int n_in,
                              void* d_out, int out_size, void* d_ws, size_t ws_size,
                              hipStream_t stream) {
    const float* mu    = (const float*)d_in[0];
    const float* sigma = (const float*)d_in[1];
    const float* y     = (const float*)d_in[2];
    float* out = (float*)d_out;

    const int nt = 2048;
    const int bs = in_sizes[0] / nt;   // 4096

    const long long base = (long long)(bs - 1) * (long long)nt;  // multiple of 4

    criterion_lastrow_kernel<<<1, 512, 0, stream>>>(
        (const float4*)(mu + base),
        (const float4*)(sigma + base),
        (const float4*)(y + base),
        out, nt, bs);
}